// Round 9
// baseline (223.868 us; speedup 1.0000x reference)
//
#include <hip/hip_runtime.h>
#include <hip/hip_bf16.h>
#include <cstdint>
#include <cstddef>

#define RANK 16

typedef __attribute__((ext_vector_type(8))) short bf16x8;   // 8 bf16 (4 VGPRs)
typedef __attribute__((ext_vector_type(4))) float f32x4;    // MFMA C/D

static __device__ __forceinline__ short f2bf(float f) {
  __hip_bfloat16 h = __float2bfloat16(f);
  return *reinterpret_cast<short*>(&h);
}

// ---------------------------------------------------------------------------
// Kernel 1: mix LoRA factors with per-(batch,split) skill weights.
//   Amt[b][r][k] = bf16( sum_s w[b][q][s] * la[q][s][d][r] ), k = q*512 + d
//   Bm[b][r][o]  = 2 * sum_s w[b][q][s] * lb[q][s][r][dd],   o = q*512 + dd
// (scaling folded into Bm; Bm stays fp32)                     [unchanged r8]
// ---------------------------------------------------------------------------
__global__ __launch_bounds__(256) void skilled_lora_mix(
    const float* __restrict__ w,       // [8][4][8]
    const float* __restrict__ la,      // [4][8][512][16]
    const float* __restrict__ lb,      // [4][8][16][512]
    __hip_bfloat16* __restrict__ Amt,  // [8][16][2048] bf16
    float* __restrict__ Bm)            // [8][16][2048] fp32, pre-scaled by 2
{
  const int j = blockIdx.x * 256 + threadIdx.x;
  if (j < 65536) {
    const int r0 = (j & 3) * 4;
    const int k  = (j >> 2) & 2047;
    const int b  = j >> 13;
    const int q  = k >> 9;
    const int d  = k & 511;
    const float* wb = w + (b * 4 + q) * 8;
    float4 acc = make_float4(0.f, 0.f, 0.f, 0.f);
#pragma unroll
    for (int s = 0; s < 8; ++s) {
      const float ws = wb[s];
      const float4 v = *reinterpret_cast<const float4*>(
          la + (size_t)(((q * 8 + s) * 512 + d) * 16 + r0));
      acc.x = fmaf(ws, v.x, acc.x);
      acc.y = fmaf(ws, v.y, acc.y);
      acc.z = fmaf(ws, v.z, acc.z);
      acc.w = fmaf(ws, v.w, acc.w);
    }
    Amt[((size_t)(b * 16 + r0 + 0)) * 2048 + k] = __float2bfloat16(acc.x);
    Amt[((size_t)(b * 16 + r0 + 1)) * 2048 + k] = __float2bfloat16(acc.y);
    Amt[((size_t)(b * 16 + r0 + 2)) * 2048 + k] = __float2bfloat16(acc.z);
    Amt[((size_t)(b * 16 + r0 + 3)) * 2048 + k] = __float2bfloat16(acc.w);
  } else {
    const int jj = j - 65536;
    const int o  = (jj & 511) * 4;
    const int r  = (jj >> 9) & 15;
    const int b  = jj >> 13;
    const int q  = o >> 9;
    const int dd = o & 511;
    const float* wb = w + (b * 4 + q) * 8;
    float4 acc = make_float4(0.f, 0.f, 0.f, 0.f);
#pragma unroll
    for (int s = 0; s < 8; ++s) {
      const float ws = wb[s];
      const float4 v = *reinterpret_cast<const float4*>(
          lb + (size_t)(((q * 8 + s) * 16 + r) * 512 + dd));
      acc.x = fmaf(ws, v.x, acc.x);
      acc.y = fmaf(ws, v.y, acc.y);
      acc.z = fmaf(ws, v.z, acc.z);
      acc.w = fmaf(ws, v.w, acc.w);
    }
    acc.x *= 2.f; acc.y *= 2.f; acc.z *= 2.f; acc.w *= 2.f;
    *reinterpret_cast<float4*>(Bm + (size_t)((b * 16 + r) * 2048 + o)) = acc;
  }
}

// ---------------------------------------------------------------------------
// Kernel 2 (fused): out[b][rows][:] = (X[b][rows][:] @ A[b]) @ B[b]
//
// ROUND-9 FUSION: phases A and B were both sub-floor as separate launches
// (A ~50us vs 25 floor; serial read-phase then write-phase leaves half the
// HBM direction idle; tmp round-trip + extra launch gap). One kernel:
//   Phase A (= validated r8 MFMA path): wave (t = 16-row tile, s = 512-k
//     split) does 16x mfma_f32_16x16x32_bf16; both fragments b128 global
//     loads (vmcnt-only, no LDS/s_load in K-loop). Symmetric-fragment trick:
//     A(lane=i+16g,j)=X[row0+t*16+i][s*512+g*8+j], B(..)=Amt[r=i][same k]
//     -> contracts over a k-bijection regardless of HW k-map. C/D layout:
//     col=lane&15 (=r), row=(lane>>4)*4+reg.
//   B-slab (16 float4/lane = 64 VGPR, L2-hot) issued before the barrier,
//     latency hidden under reduce.
//   Reduce: 4 k-split partials (LDS, stride-17) -> tmpl[32][16].
//   Phase B: wave owns 256 cols; per row 4x broadcast ds_read_b128 of tmpl
//     + 64 FMA + coalesced float4 store.
// 512 thr = 8 waves, 32 rows/block, grid 512 = 2 blocks/CU -> 4 waves/SIMD.
// __launch_bounds__(512,4) caps VGPR at 128 (B4=64 + ~40 live, no spill).
// ---------------------------------------------------------------------------
__global__ __launch_bounds__(512, 4) void lora_fused(
    const float* __restrict__ X,            // [8][2048][2048]
    const __hip_bfloat16* __restrict__ Amt, // [8][16][2048] bf16
    const float* __restrict__ Bm,           // [8][16][2048] fp32 (pre-scaled)
    float* __restrict__ out)                // [8][2048][2048]
{
  __shared__ float part[4][32][17];                  // 8.7 KB
  __shared__ __align__(16) float tmpl[32][RANK];     // 2 KB

  const int tid  = threadIdx.x;
  const int lane = tid & 63;
  const int wv   = tid >> 6;               // 0..7
  const int b    = blockIdx.x >> 6;        // 8 batches x 64 row-tiles
  const int row0 = (blockIdx.x & 63) * 32;
  const int t    = wv >> 2;                // 16-row tile 0..1
  const int s    = wv & 3;                 // 512-k split 0..3
  const int m    = lane & 15;              // row-in-tile / r
  const int g    = lane >> 4;              // k-subgroup 0..3

  // ---------------- phase A: MFMA over this wave's (tile, k-split) ----------
  const float* Xp = X + ((size_t)(b * 2048 + row0 + t * 16 + m)) * 2048
                      + s * 512 + g * 8;
  const __hip_bfloat16* Ap = Amt + ((size_t)(b * 16 + m)) * 2048
                                 + s * 512 + g * 8;

  f32x4 acc = {0.f, 0.f, 0.f, 0.f};
#pragma unroll 4
  for (int kg = 0; kg < 16; ++kg) {        // 16 x (K=32) = 512 k
    const float4 xlo = *reinterpret_cast<const float4*>(Xp + (size_t)kg * 32);
    const float4 xhi = *reinterpret_cast<const float4*>(Xp + (size_t)kg * 32 + 4);
    bf16x8 afrag;
    afrag[0] = f2bf(xlo.x); afrag[1] = f2bf(xlo.y);
    afrag[2] = f2bf(xlo.z); afrag[3] = f2bf(xlo.w);
    afrag[4] = f2bf(xhi.x); afrag[5] = f2bf(xhi.y);
    afrag[6] = f2bf(xhi.z); afrag[7] = f2bf(xhi.w);
    const bf16x8 bfrag = *reinterpret_cast<const bf16x8*>(Ap + (size_t)kg * 32);
    acc = __builtin_amdgcn_mfma_f32_16x16x32_bf16(afrag, bfrag, acc, 0, 0, 0);
  }

  // park partials: lane holds tmp[row = t*16 + g*4+v][r = m] for split s
#pragma unroll
  for (int v = 0; v < 4; ++v)
    part[s][t * 16 + g * 4 + v][m] = acc[v];

  // ---------------- B-slab load (L2-hot), hidden under reduce ---------------
  const int o0 = wv * 256 + lane * 4;
  const float* Bb = Bm + (size_t)b * (RANK * 2048) + o0;
  float4 B4[RANK];
#pragma unroll
  for (int r = 0; r < RANK; ++r)
    B4[r] = *reinterpret_cast<const float4*>(Bb + (size_t)r * 2048);

  __syncthreads();

  // ---------------- reduce 4 k-splits -> tmpl[32][16] -----------------------
  {
    const int row = tid >> 4;              // 0..31 (512 threads, 512 elems)
    const int r   = tid & 15;
    tmpl[row][r] = part[0][row][r] + part[1][row][r]
                 + part[2][row][r] + part[3][row][r];
  }
  __syncthreads();

  // ---------------- phase B: 32 rows x 256 cols per wave --------------------
  float* op = out + ((size_t)(b * 2048 + row0)) * 2048 + o0;
#pragma unroll 2
  for (int rr = 0; rr < 32; ++rr) {
    const float4 t0 = *reinterpret_cast<const float4*>(&tmpl[rr][0]);   // LDS
    const float4 t1 = *reinterpret_cast<const float4*>(&tmpl[rr][4]);   // bcast
    const float4 t2 = *reinterpret_cast<const float4*>(&tmpl[rr][8]);
    const float4 t3 = *reinterpret_cast<const float4*>(&tmpl[rr][12]);
    float4 a = make_float4(0.f, 0.f, 0.f, 0.f);
    a.x = fmaf(t0.x, B4[0].x, a.x);  a.y = fmaf(t0.x, B4[0].y, a.y);
    a.z = fmaf(t0.x, B4[0].z, a.z);  a.w = fmaf(t0.x, B4[0].w, a.w);
    a.x = fmaf(t0.y, B4[1].x, a.x);  a.y = fmaf(t0.y, B4[1].y, a.y);
    a.z = fmaf(t0.y, B4[1].z, a.z);  a.w = fmaf(t0.y, B4[1].w, a.w);
    a.x = fmaf(t0.z, B4[2].x, a.x);  a.y = fmaf(t0.z, B4[2].y, a.y);
    a.z = fmaf(t0.z, B4[2].z, a.z);  a.w = fmaf(t0.z, B4[2].w, a.w);
    a.x = fmaf(t0.w, B4[3].x, a.x);  a.y = fmaf(t0.w, B4[3].y, a.y);
    a.z = fmaf(t0.w, B4[3].z, a.z);  a.w = fmaf(t0.w, B4[3].w, a.w);
    a.x = fmaf(t1.x, B4[4].x, a.x);  a.y = fmaf(t1.x, B4[4].y, a.y);
    a.z = fmaf(t1.x, B4[4].z, a.z);  a.w = fmaf(t1.x, B4[4].w, a.w);
    a.x = fmaf(t1.y, B4[5].x, a.x);  a.y = fmaf(t1.y, B4[5].y, a.y);
    a.z = fmaf(t1.y, B4[5].z, a.z);  a.w = fmaf(t1.y, B4[5].w, a.w);
    a.x = fmaf(t1.z, B4[6].x, a.x);  a.y = fmaf(t1.z, B4[6].y, a.y);
    a.z = fmaf(t1.z, B4[6].z, a.z);  a.w = fmaf(t1.z, B4[6].w, a.w);
    a.x = fmaf(t1.w, B4[7].x, a.x);  a.y = fmaf(t1.w, B4[7].y, a.y);
    a.z = fmaf(t1.w, B4[7].z, a.z);  a.w = fmaf(t1.w, B4[7].w, a.w);
    a.x = fmaf(t2.x, B4[8].x, a.x);  a.y = fmaf(t2.x, B4[8].y, a.y);
    a.z = fmaf(t2.x, B4[8].z, a.z);  a.w = fmaf(t2.x, B4[8].w, a.w);
    a.x = fmaf(t2.y, B4[9].x, a.x);  a.y = fmaf(t2.y, B4[9].y, a.y);
    a.z = fmaf(t2.y, B4[9].z, a.z);  a.w = fmaf(t2.y, B4[9].w, a.w);
    a.x = fmaf(t2.z, B4[10].x, a.x); a.y = fmaf(t2.z, B4[10].y, a.y);
    a.z = fmaf(t2.z, B4[10].z, a.z); a.w = fmaf(t2.z, B4[10].w, a.w);
    a.x = fmaf(t2.w, B4[11].x, a.x); a.y = fmaf(t2.w, B4[11].y, a.y);
    a.z = fmaf(t2.w, B4[11].z, a.z); a.w = fmaf(t2.w, B4[11].w, a.w);
    a.x = fmaf(t3.x, B4[12].x, a.x); a.y = fmaf(t3.x, B4[12].y, a.y);
    a.z = fmaf(t3.x, B4[12].z, a.z); a.w = fmaf(t3.x, B4[12].w, a.w);
    a.x = fmaf(t3.y, B4[13].x, a.x); a.y = fmaf(t3.y, B4[13].y, a.y);
    a.z = fmaf(t3.y, B4[13].z, a.z); a.w = fmaf(t3.y, B4[13].w, a.w);
    a.x = fmaf(t3.z, B4[14].x, a.x); a.y = fmaf(t3.z, B4[14].y, a.y);
    a.z = fmaf(t3.z, B4[14].z, a.z); a.w = fmaf(t3.z, B4[14].w, a.w);
    a.x = fmaf(t3.w, B4[15].x, a.x); a.y = fmaf(t3.w, B4[15].y, a.y);
    a.z = fmaf(t3.w, B4[15].z, a.z); a.w = fmaf(t3.w, B4[15].w, a.w);
    *reinterpret_cast<float4*>(op + (size_t)rr * 2048) = a;
  }
}

// ---------------------------------------------------------------------------
extern "C" void kernel_launch(void* const* d_in, const int* in_sizes, int n_in,
                              void* d_out, int out_size, void* d_ws, size_t ws_size,
                              hipStream_t stream) {
  const float* input = (const float*)d_in[0];   // [8][2048][2048]
  const float* w     = (const float*)d_in[1];   // [8][4][8]
  const float* la    = (const float*)d_in[2];   // [4][8][512][16]
  const float* lb    = (const float*)d_in[3];   // [4][8][16][512]
  float* outp = (float*)d_out;

  __hip_bfloat16* Amt = (__hip_bfloat16*)d_ws;                    // 512 KB
  float* Bm = (float*)((char*)d_ws + (size_t)8 * 16 * 2048 * 2);  // 1 MB

  skilled_lora_mix<<<512, 256, 0, stream>>>(w, la, lb, Amt, Bm);
  lora_fused<<<512, 512, 0, stream>>>(input, Amt, Bm, outp);
}

// Round 10
// 83.207 us; speedup vs baseline: 2.6905x; 2.6905x over previous
//
#include <hip/hip_runtime.h>
#include <hip/hip_bf16.h>
#include <cstdint>
#include <cstddef>

#define RANK 16

typedef __attribute__((ext_vector_type(8))) short bf16x8;   // 8 bf16 (4 VGPRs)
typedef __attribute__((ext_vector_type(4))) float f32x4;    // MFMA C/D

static __device__ __forceinline__ short f2bf(float f) {
  __hip_bfloat16 h = __float2bfloat16(f);
  return *reinterpret_cast<short*>(&h);
}

// ---------------------------------------------------------------------------
// Kernel 1: mix LoRA factors with per-(batch,split) skill weights.
//   Amt[b][r][k] = bf16( sum_s w[b][q][s] * la[q][s][d][r] ), k = q*512 + d
//   Bm[b][r][o]  = 2 * sum_s w[b][q][s] * lb[q][s][r][dd],   o = q*512 + dd
// (scaling folded into Bm; Bm stays fp32)                     [unchanged r8]
// ---------------------------------------------------------------------------
__global__ __launch_bounds__(256) void skilled_lora_mix(
    const float* __restrict__ w,       // [8][4][8]
    const float* __restrict__ la,      // [4][8][512][16]
    const float* __restrict__ lb,      // [4][8][16][512]
    __hip_bfloat16* __restrict__ Amt,  // [8][16][2048] bf16
    float* __restrict__ Bm)            // [8][16][2048] fp32, pre-scaled by 2
{
  const int j = blockIdx.x * 256 + threadIdx.x;
  if (j < 65536) {
    const int r0 = (j & 3) * 4;
    const int k  = (j >> 2) & 2047;
    const int b  = j >> 13;
    const int q  = k >> 9;
    const int d  = k & 511;
    const float* wb = w + (b * 4 + q) * 8;
    float4 acc = make_float4(0.f, 0.f, 0.f, 0.f);
#pragma unroll
    for (int s = 0; s < 8; ++s) {
      const float ws = wb[s];
      const float4 v = *reinterpret_cast<const float4*>(
          la + (size_t)(((q * 8 + s) * 512 + d) * 16 + r0));
      acc.x = fmaf(ws, v.x, acc.x);
      acc.y = fmaf(ws, v.y, acc.y);
      acc.z = fmaf(ws, v.z, acc.z);
      acc.w = fmaf(ws, v.w, acc.w);
    }
    Amt[((size_t)(b * 16 + r0 + 0)) * 2048 + k] = __float2bfloat16(acc.x);
    Amt[((size_t)(b * 16 + r0 + 1)) * 2048 + k] = __float2bfloat16(acc.y);
    Amt[((size_t)(b * 16 + r0 + 2)) * 2048 + k] = __float2bfloat16(acc.z);
    Amt[((size_t)(b * 16 + r0 + 3)) * 2048 + k] = __float2bfloat16(acc.w);
  } else {
    const int jj = j - 65536;
    const int o  = (jj & 511) * 4;
    const int r  = (jj >> 9) & 15;
    const int b  = jj >> 13;
    const int q  = o >> 9;
    const int dd = o & 511;
    const float* wb = w + (b * 4 + q) * 8;
    float4 acc = make_float4(0.f, 0.f, 0.f, 0.f);
#pragma unroll
    for (int s = 0; s < 8; ++s) {
      const float ws = wb[s];
      const float4 v = *reinterpret_cast<const float4*>(
          lb + (size_t)(((q * 8 + s) * 16 + r) * 512 + dd));
      acc.x = fmaf(ws, v.x, acc.x);
      acc.y = fmaf(ws, v.y, acc.y);
      acc.z = fmaf(ws, v.z, acc.z);
      acc.w = fmaf(ws, v.w, acc.w);
    }
    acc.x *= 2.f; acc.y *= 2.f; acc.z *= 2.f; acc.w *= 2.f;
    *reinterpret_cast<float4*>(Bm + (size_t)((b * 16 + r) * 2048 + o)) = acc;
  }
}

// ---------------------------------------------------------------------------
// Kernel 2 (fused): out[b][rows][:] = (X[b][rows][:] @ A[b]) @ B[b]
//
// ROUND-10 FIX: round 9's ONLY defect was __launch_bounds__(512,4) -> the
// allocator clamped to 64 VGPR and spilled the B-slab (FETCH 457MB, WRITE
// 264MB, VALUBusy 5%). (512,2) is session-proven safe: round 1 used it with
// the same 64-VGPR B-slab and got VGPR_Count=108, no spill. Actual occupancy
// at ~110 VGPR is still 4 waves/SIMD (128-reg bucket). Nothing else changed.
//
//   Phase A: wave (t = 16-row tile, s = 512-k split) does 16x
//     mfma_f32_16x16x32_bf16; both fragments b128 global loads (vmcnt-only,
//     no LDS/s_load in K-loop). Symmetric-fragment trick:
//     A(lane=i+16g,j)=X[row0+t*16+i][s*512+g*8+j], B(..)=Amt[r=i][same k]
//     -> contracts over a k-bijection regardless of HW k-map. C/D layout:
//     col=lane&15 (=r), row=(lane>>4)*4+reg.
//   B-slab (16 float4/lane = 64 VGPR, L2-hot) issued before the barrier,
//     latency hidden under reduce.
//   Reduce: 4 k-split partials (LDS, stride-17) -> tmpl[32][16].
//   Phase B: wave owns 256 cols; per row 4x broadcast ds_read_b128 of tmpl
//     + 64 FMA + coalesced float4 store.
// 512 thr = 8 waves, 32 rows/block, grid 512 = 2 blocks/CU.
// ---------------------------------------------------------------------------
__global__ __launch_bounds__(512, 2) void lora_fused(
    const float* __restrict__ X,            // [8][2048][2048]
    const __hip_bfloat16* __restrict__ Amt, // [8][16][2048] bf16
    const float* __restrict__ Bm,           // [8][16][2048] fp32 (pre-scaled)
    float* __restrict__ out)                // [8][2048][2048]
{
  __shared__ float part[4][32][17];                  // 8.7 KB
  __shared__ __align__(16) float tmpl[32][RANK];     // 2 KB

  const int tid  = threadIdx.x;
  const int lane = tid & 63;
  const int wv   = tid >> 6;               // 0..7
  const int b    = blockIdx.x >> 6;        // 8 batches x 64 row-tiles
  const int row0 = (blockIdx.x & 63) * 32;
  const int t    = wv >> 2;                // 16-row tile 0..1
  const int s    = wv & 3;                 // 512-k split 0..3
  const int m    = lane & 15;              // row-in-tile / r
  const int g    = lane >> 4;              // k-subgroup 0..3

  // ---------------- phase A: MFMA over this wave's (tile, k-split) ----------
  const float* Xp = X + ((size_t)(b * 2048 + row0 + t * 16 + m)) * 2048
                      + s * 512 + g * 8;
  const __hip_bfloat16* Ap = Amt + ((size_t)(b * 16 + m)) * 2048
                                 + s * 512 + g * 8;

  f32x4 acc = {0.f, 0.f, 0.f, 0.f};
#pragma unroll 4
  for (int kg = 0; kg < 16; ++kg) {        // 16 x (K=32) = 512 k
    const float4 xlo = *reinterpret_cast<const float4*>(Xp + (size_t)kg * 32);
    const float4 xhi = *reinterpret_cast<const float4*>(Xp + (size_t)kg * 32 + 4);
    bf16x8 afrag;
    afrag[0] = f2bf(xlo.x); afrag[1] = f2bf(xlo.y);
    afrag[2] = f2bf(xlo.z); afrag[3] = f2bf(xlo.w);
    afrag[4] = f2bf(xhi.x); afrag[5] = f2bf(xhi.y);
    afrag[6] = f2bf(xhi.z); afrag[7] = f2bf(xhi.w);
    const bf16x8 bfrag = *reinterpret_cast<const bf16x8*>(Ap + (size_t)kg * 32);
    acc = __builtin_amdgcn_mfma_f32_16x16x32_bf16(afrag, bfrag, acc, 0, 0, 0);
  }

  // park partials: lane holds tmp[row = t*16 + g*4+v][r = m] for split s
#pragma unroll
  for (int v = 0; v < 4; ++v)
    part[s][t * 16 + g * 4 + v][m] = acc[v];

  // ---------------- B-slab load (L2-hot), hidden under reduce ---------------
  const int o0 = wv * 256 + lane * 4;
  const float* Bb = Bm + (size_t)b * (RANK * 2048) + o0;
  float4 B4[RANK];
#pragma unroll
  for (int r = 0; r < RANK; ++r)
    B4[r] = *reinterpret_cast<const float4*>(Bb + (size_t)r * 2048);

  __syncthreads();

  // ---------------- reduce 4 k-splits -> tmpl[32][16] -----------------------
  {
    const int row = tid >> 4;              // 0..31 (512 threads, 512 elems)
    const int r   = tid & 15;
    tmpl[row][r] = part[0][row][r] + part[1][row][r]
                 + part[2][row][r] + part[3][row][r];
  }
  __syncthreads();

  // ---------------- phase B: 32 rows x 256 cols per wave --------------------
  float* op = out + ((size_t)(b * 2048 + row0)) * 2048 + o0;
#pragma unroll 2
  for (int rr = 0; rr < 32; ++rr) {
    const float4 t0 = *reinterpret_cast<const float4*>(&tmpl[rr][0]);   // LDS
    const float4 t1 = *reinterpret_cast<const float4*>(&tmpl[rr][4]);   // bcast
    const float4 t2 = *reinterpret_cast<const float4*>(&tmpl[rr][8]);
    const float4 t3 = *reinterpret_cast<const float4*>(&tmpl[rr][12]);
    float4 a = make_float4(0.f, 0.f, 0.f, 0.f);
    a.x = fmaf(t0.x, B4[0].x, a.x);  a.y = fmaf(t0.x, B4[0].y, a.y);
    a.z = fmaf(t0.x, B4[0].z, a.z);  a.w = fmaf(t0.x, B4[0].w, a.w);
    a.x = fmaf(t0.y, B4[1].x, a.x);  a.y = fmaf(t0.y, B4[1].y, a.y);
    a.z = fmaf(t0.y, B4[1].z, a.z);  a.w = fmaf(t0.y, B4[1].w, a.w);
    a.x = fmaf(t0.z, B4[2].x, a.x);  a.y = fmaf(t0.z, B4[2].y, a.y);
    a.z = fmaf(t0.z, B4[2].z, a.z);  a.w = fmaf(t0.z, B4[2].w, a.w);
    a.x = fmaf(t0.w, B4[3].x, a.x);  a.y = fmaf(t0.w, B4[3].y, a.y);
    a.z = fmaf(t0.w, B4[3].z, a.z);  a.w = fmaf(t0.w, B4[3].w, a.w);
    a.x = fmaf(t1.x, B4[4].x, a.x);  a.y = fmaf(t1.x, B4[4].y, a.y);
    a.z = fmaf(t1.x, B4[4].z, a.z);  a.w = fmaf(t1.x, B4[4].w, a.w);
    a.x = fmaf(t1.y, B4[5].x, a.x);  a.y = fmaf(t1.y, B4[5].y, a.y);
    a.z = fmaf(t1.y, B4[5].z, a.z);  a.w = fmaf(t1.y, B4[5].w, a.w);
    a.x = fmaf(t1.z, B4[6].x, a.x);  a.y = fmaf(t1.z, B4[6].y, a.y);
    a.z = fmaf(t1.z, B4[6].z, a.z);  a.w = fmaf(t1.z, B4[6].w, a.w);
    a.x = fmaf(t1.w, B4[7].x, a.x);  a.y = fmaf(t1.w, B4[7].y, a.y);
    a.z = fmaf(t1.w, B4[7].z, a.z);  a.w = fmaf(t1.w, B4[7].w, a.w);
    a.x = fmaf(t2.x, B4[8].x, a.x);  a.y = fmaf(t2.x, B4[8].y, a.y);
    a.z = fmaf(t2.x, B4[8].z, a.z);  a.w = fmaf(t2.x, B4[8].w, a.w);
    a.x = fmaf(t2.y, B4[9].x, a.x);  a.y = fmaf(t2.y, B4[9].y, a.y);
    a.z = fmaf(t2.y, B4[9].z, a.z);  a.w = fmaf(t2.y, B4[9].w, a.w);
    a.x = fmaf(t2.z, B4[10].x, a.x); a.y = fmaf(t2.z, B4[10].y, a.y);
    a.z = fmaf(t2.z, B4[10].z, a.z); a.w = fmaf(t2.z, B4[10].w, a.w);
    a.x = fmaf(t2.w, B4[11].x, a.x); a.y = fmaf(t2.w, B4[11].y, a.y);
    a.z = fmaf(t2.w, B4[11].z, a.z); a.w = fmaf(t2.w, B4[11].w, a.w);
    a.x = fmaf(t3.x, B4[12].x, a.x); a.y = fmaf(t3.x, B4[12].y, a.y);
    a.z = fmaf(t3.x, B4[12].z, a.z); a.w = fmaf(t3.x, B4[12].w, a.w);
    a.x = fmaf(t3.y, B4[13].x, a.x); a.y = fmaf(t3.y, B4[13].y, a.y);
    a.z = fmaf(t3.y, B4[13].z, a.z); a.w = fmaf(t3.y, B4[13].w, a.w);
    a.x = fmaf(t3.z, B4[14].x, a.x); a.y = fmaf(t3.z, B4[14].y, a.y);
    a.z = fmaf(t3.z, B4[14].z, a.z); a.w = fmaf(t3.z, B4[14].w, a.w);
    a.x = fmaf(t3.w, B4[15].x, a.x); a.y = fmaf(t3.w, B4[15].y, a.y);
    a.z = fmaf(t3.w, B4[15].z, a.z); a.w = fmaf(t3.w, B4[15].w, a.w);
    *reinterpret_cast<float4*>(op + (size_t)rr * 2048) = a;
  }
}

// ---------------------------------------------------------------------------
extern "C" void kernel_launch(void* const* d_in, const int* in_sizes, int n_in,
                              void* d_out, int out_size, void* d_ws, size_t ws_size,
                              hipStream_t stream) {
  const float* input = (const float*)d_in[0];   // [8][2048][2048]
  const float* w     = (const float*)d_in[1];   // [8][4][8]
  const float* la    = (const float*)d_in[2];   // [4][8][512][16]
  const float* lb    = (const float*)d_in[3];   // [4][8][16][512]
  float* outp = (float*)d_out;

  __hip_bfloat16* Amt = (__hip_bfloat16*)d_ws;                    // 512 KB
  float* Bm = (float*)((char*)d_ws + (size_t)8 * 16 * 2048 * 2);  // 1 MB

  skilled_lora_mix<<<512, 256, 0, stream>>>(w, la, lb, Amt, Bm);
  lora_fused<<<512, 512, 0, stream>>>(input, Amt, Bm, outp);
}

// Round 11
// 82.231 us; speedup vs baseline: 2.7224x; 1.0119x over previous
//
#include <hip/hip_runtime.h>
#include <hip/hip_bf16.h>
#include <cstdint>
#include <cstddef>

#define RANK 16

typedef __attribute__((ext_vector_type(8))) short bf16x8;   // 8 bf16 (4 VGPRs)
typedef __attribute__((ext_vector_type(4))) float f32x4;    // MFMA C/D

static __device__ __forceinline__ short f2bf(float f) {
  __hip_bfloat16 h = __float2bfloat16(f);
  return *reinterpret_cast<short*>(&h);
}

// ---------------------------------------------------------------------------
// Kernel 1: mix LoRA factors with per-(batch,split) skill weights.
//   Amt[b][r][k] = bf16( sum_s w[b][q][s] * la[q][s][d][r] ), k = q*512 + d
//   Bm[b][r][o]  = 2 * sum_s w[b][q][s] * lb[q][s][r][dd],   o = q*512 + dd
// (scaling folded into Bm; Bm stays fp32)                     [unchanged r8]
// ---------------------------------------------------------------------------
__global__ __launch_bounds__(256) void skilled_lora_mix(
    const float* __restrict__ w,       // [8][4][8]
    const float* __restrict__ la,      // [4][8][512][16]
    const float* __restrict__ lb,      // [4][8][16][512]
    __hip_bfloat16* __restrict__ Amt,  // [8][16][2048] bf16
    float* __restrict__ Bm)            // [8][16][2048] fp32, pre-scaled by 2
{
  const int j = blockIdx.x * 256 + threadIdx.x;
  if (j < 65536) {
    const int r0 = (j & 3) * 4;
    const int k  = (j >> 2) & 2047;
    const int b  = j >> 13;
    const int q  = k >> 9;
    const int d  = k & 511;
    const float* wb = w + (b * 4 + q) * 8;
    float4 acc = make_float4(0.f, 0.f, 0.f, 0.f);
#pragma unroll
    for (int s = 0; s < 8; ++s) {
      const float ws = wb[s];
      const float4 v = *reinterpret_cast<const float4*>(
          la + (size_t)(((q * 8 + s) * 512 + d) * 16 + r0));
      acc.x = fmaf(ws, v.x, acc.x);
      acc.y = fmaf(ws, v.y, acc.y);
      acc.z = fmaf(ws, v.z, acc.z);
      acc.w = fmaf(ws, v.w, acc.w);
    }
    Amt[((size_t)(b * 16 + r0 + 0)) * 2048 + k] = __float2bfloat16(acc.x);
    Amt[((size_t)(b * 16 + r0 + 1)) * 2048 + k] = __float2bfloat16(acc.y);
    Amt[((size_t)(b * 16 + r0 + 2)) * 2048 + k] = __float2bfloat16(acc.z);
    Amt[((size_t)(b * 16 + r0 + 3)) * 2048 + k] = __float2bfloat16(acc.w);
  } else {
    const int jj = j - 65536;
    const int o  = (jj & 511) * 4;
    const int r  = (jj >> 9) & 15;
    const int b  = jj >> 13;
    const int q  = o >> 9;
    const int dd = o & 511;
    const float* wb = w + (b * 4 + q) * 8;
    float4 acc = make_float4(0.f, 0.f, 0.f, 0.f);
#pragma unroll
    for (int s = 0; s < 8; ++s) {
      const float ws = wb[s];
      const float4 v = *reinterpret_cast<const float4*>(
          lb + (size_t)(((q * 8 + s) * 16 + r) * 512 + dd));
      acc.x = fmaf(ws, v.x, acc.x);
      acc.y = fmaf(ws, v.y, acc.y);
      acc.z = fmaf(ws, v.z, acc.z);
      acc.w = fmaf(ws, v.w, acc.w);
    }
    acc.x *= 2.f; acc.y *= 2.f; acc.z *= 2.f; acc.w *= 2.f;
    *reinterpret_cast<float4*>(Bm + (size_t)((b * 16 + r) * 2048 + o)) = acc;
  }
}

// ---------------------------------------------------------------------------
// Kernel 2 (phase A, MFMA): partial tmp over a 1024-k half.
//
// ROUND-11: de-fused. r10's fusion tied phase A occupancy to phase B's
// 64-VGPR B-slab (VGPR 108 -> 16 waves/CU) and barrier-serialized the read
// and write phases. Phase A standalone has no B-slab: live set ~48 VGPR.
//   grid 2048 = 8 batches x 128 row-tiles(16) x 2 k-splits(1024), 256 thr.
//   __launch_bounds__(256,8): cap 64 VGPR -> 8 blocks/CU = 32 waves/CU.
//   unroll 2 keeps transient regs ~32 (6 loads in flight x 32 waves/CU
//   >> Little's-law in-flight requirement at ~6 TB/s).
// Each k-split writes its own partial buffer (no cross-block races);
// phase B sums the two. MFMA mechanics identical to r8 (validated):
// symmetric-fragment trick, C/D col=lane&15 (=r), row=(lane>>4)*4+reg.
// ---------------------------------------------------------------------------
__global__ __launch_bounds__(256, 8) void lora_phase_a(
    const float* __restrict__ X,           // [8][2048][2048]
    const __hip_bfloat16* __restrict__ Amt,// [8][16][2048] bf16
    float* __restrict__ tmp_p)             // [2][8][2048][16] partials
{
  __shared__ float part[4][16][17];        // 4.4 KB

  const int tid  = threadIdx.x;
  const int lane = tid & 63;
  const int wv   = tid >> 6;               // 0..3: 256-k sub-window
  const int b    = blockIdx.x >> 8;        // 8 batches
  const int tile = (blockIdx.x >> 1) & 127;
  const int ks   = blockIdx.x & 1;         // k-split 0..1
  const int row0 = tile * 16;
  const int k0   = ks * 1024 + wv * 256;
  const int m    = lane & 15;              // row-in-tile / r
  const int g    = lane >> 4;              // k-subgroup 0..3

  const float* Xp = X + ((size_t)(b * 2048 + row0 + m)) * 2048 + k0 + g * 8;
  const __hip_bfloat16* Ap = Amt + ((size_t)(b * 16 + m)) * 2048 + k0 + g * 8;

  f32x4 acc = {0.f, 0.f, 0.f, 0.f};
#pragma unroll 2
  for (int kg = 0; kg < 8; ++kg) {         // 8 x (K=32) = 256 k per wave
    const float4 xlo = *reinterpret_cast<const float4*>(Xp + (size_t)kg * 32);
    const float4 xhi = *reinterpret_cast<const float4*>(Xp + (size_t)kg * 32 + 4);
    bf16x8 afrag;
    afrag[0] = f2bf(xlo.x); afrag[1] = f2bf(xlo.y);
    afrag[2] = f2bf(xlo.z); afrag[3] = f2bf(xlo.w);
    afrag[4] = f2bf(xhi.x); afrag[5] = f2bf(xhi.y);
    afrag[6] = f2bf(xhi.z); afrag[7] = f2bf(xhi.w);
    const bf16x8 bfrag = *reinterpret_cast<const bf16x8*>(Ap + (size_t)kg * 32);
    acc = __builtin_amdgcn_mfma_f32_16x16x32_bf16(afrag, bfrag, acc, 0, 0, 0);
  }

  // D(lane, reg v) -> partial tmp[row = g*4+v][r = m] for sub-window wv
#pragma unroll
  for (int v = 0; v < 4; ++v)
    part[wv][g * 4 + v][m] = acc[v];
  __syncthreads();

  // 256 threads == 256 (row, r) pairs: reduce the 4 sub-windows
  const int row = tid >> 4;                // 0..15
  const int r   = tid & 15;
  const float s = part[0][row][r] + part[1][row][r]
                + part[2][row][r] + part[3][row][r];
  tmp_p[((size_t)((ks * 8 + b) * 2048 + row0 + row)) * RANK + r] = s;
}

// ---------------------------------------------------------------------------
// Kernel 3 (phase B): out[b][row][o] = sum_r (tmp0+tmp1)[b][row][r] * Bm[r][o]
// r8-proven structure (~28us, near write floor): grid 2048, 16 rows/block,
// B-slab in 64 VGPR, block-uniform scalar tmp loads. Added: sum of the two
// k-split partials (scalar-pipe loads + 16 VALU adds per row, negligible).
// ---------------------------------------------------------------------------
__global__ __launch_bounds__(256, 2) void lora_phase_b(
    const float* __restrict__ tmp_p, // [2][8][2048][16] partials
    const float* __restrict__ Bm,    // [8][16][2048] (pre-scaled by 2)
    float* __restrict__ out)         // [8][2048][2048]
{
  const int tid  = threadIdx.x;
  const int b    = blockIdx.x >> 8;          // 8 batches x 256 blocks
  const int oh   = (blockIdx.x >> 7) & 1;    // column half
  const int rt   = blockIdx.x & 127;         // row tile
  const int row0 = rt * 16;
  const int o0   = oh * 1024 + tid * 4;

  const float* Bb = Bm + (size_t)b * (RANK * 2048) + o0;
  float4 B4[RANK];
#pragma unroll
  for (int r = 0; r < RANK; ++r)
    B4[r] = *reinterpret_cast<const float4*>(Bb + (size_t)r * 2048);

  const float* tp0 = tmp_p + ((size_t)(b * 2048 + row0)) * RANK;
  const float* tp1 = tmp_p + ((size_t)((8 + b) * 2048 + row0)) * RANK;
  float* op = out + ((size_t)(b * 2048 + row0)) * 2048 + o0;

#pragma unroll 4
  for (int rr = 0; rr < 16; ++rr) {
    const float4 u0 = *reinterpret_cast<const float4*>(tp0 + rr * RANK);
    const float4 u1 = *reinterpret_cast<const float4*>(tp0 + rr * RANK + 4);
    const float4 u2 = *reinterpret_cast<const float4*>(tp0 + rr * RANK + 8);
    const float4 u3 = *reinterpret_cast<const float4*>(tp0 + rr * RANK + 12);
    const float4 v0 = *reinterpret_cast<const float4*>(tp1 + rr * RANK);
    const float4 v1 = *reinterpret_cast<const float4*>(tp1 + rr * RANK + 4);
    const float4 v2 = *reinterpret_cast<const float4*>(tp1 + rr * RANK + 8);
    const float4 v3 = *reinterpret_cast<const float4*>(tp1 + rr * RANK + 12);
    const float4 t0 = make_float4(u0.x + v0.x, u0.y + v0.y, u0.z + v0.z, u0.w + v0.w);
    const float4 t1 = make_float4(u1.x + v1.x, u1.y + v1.y, u1.z + v1.z, u1.w + v1.w);
    const float4 t2 = make_float4(u2.x + v2.x, u2.y + v2.y, u2.z + v2.z, u2.w + v2.w);
    const float4 t3 = make_float4(u3.x + v3.x, u3.y + v3.y, u3.z + v3.z, u3.w + v3.w);
    float4 a = make_float4(0.f, 0.f, 0.f, 0.f);
    a.x = fmaf(t0.x, B4[0].x, a.x);  a.y = fmaf(t0.x, B4[0].y, a.y);
    a.z = fmaf(t0.x, B4[0].z, a.z);  a.w = fmaf(t0.x, B4[0].w, a.w);
    a.x = fmaf(t0.y, B4[1].x, a.x);  a.y = fmaf(t0.y, B4[1].y, a.y);
    a.z = fmaf(t0.y, B4[1].z, a.z);  a.w = fmaf(t0.y, B4[1].w, a.w);
    a.x = fmaf(t0.z, B4[2].x, a.x);  a.y = fmaf(t0.z, B4[2].y, a.y);
    a.z = fmaf(t0.z, B4[2].z, a.z);  a.w = fmaf(t0.z, B4[2].w, a.w);
    a.x = fmaf(t0.w, B4[3].x, a.x);  a.y = fmaf(t0.w, B4[3].y, a.y);
    a.z = fmaf(t0.w, B4[3].z, a.z);  a.w = fmaf(t0.w, B4[3].w, a.w);
    a.x = fmaf(t1.x, B4[4].x, a.x);  a.y = fmaf(t1.x, B4[4].y, a.y);
    a.z = fmaf(t1.x, B4[4].z, a.z);  a.w = fmaf(t1.x, B4[4].w, a.w);
    a.x = fmaf(t1.y, B4[5].x, a.x);  a.y = fmaf(t1.y, B4[5].y, a.y);
    a.z = fmaf(t1.y, B4[5].z, a.z);  a.w = fmaf(t1.y, B4[5].w, a.w);
    a.x = fmaf(t1.z, B4[6].x, a.x);  a.y = fmaf(t1.z, B4[6].y, a.y);
    a.z = fmaf(t1.z, B4[6].z, a.z);  a.w = fmaf(t1.z, B4[6].w, a.w);
    a.x = fmaf(t1.w, B4[7].x, a.x);  a.y = fmaf(t1.w, B4[7].y, a.y);
    a.z = fmaf(t1.w, B4[7].z, a.z);  a.w = fmaf(t1.w, B4[7].w, a.w);
    a.x = fmaf(t2.x, B4[8].x, a.x);  a.y = fmaf(t2.x, B4[8].y, a.y);
    a.z = fmaf(t2.x, B4[8].z, a.z);  a.w = fmaf(t2.x, B4[8].w, a.w);
    a.x = fmaf(t2.y, B4[9].x, a.x);  a.y = fmaf(t2.y, B4[9].y, a.y);
    a.z = fmaf(t2.y, B4[9].z, a.z);  a.w = fmaf(t2.y, B4[9].w, a.w);
    a.x = fmaf(t2.z, B4[10].x, a.x); a.y = fmaf(t2.z, B4[10].y, a.y);
    a.z = fmaf(t2.z, B4[10].z, a.z); a.w = fmaf(t2.z, B4[10].w, a.w);
    a.x = fmaf(t2.w, B4[11].x, a.x); a.y = fmaf(t2.w, B4[11].y, a.y);
    a.z = fmaf(t2.w, B4[11].z, a.z); a.w = fmaf(t2.w, B4[11].w, a.w);
    a.x = fmaf(t3.x, B4[12].x, a.x); a.y = fmaf(t3.x, B4[12].y, a.y);
    a.z = fmaf(t3.x, B4[12].z, a.z); a.w = fmaf(t3.x, B4[12].w, a.w);
    a.x = fmaf(t3.y, B4[13].x, a.x); a.y = fmaf(t3.y, B4[13].y, a.y);
    a.z = fmaf(t3.y, B4[13].z, a.z); a.w = fmaf(t3.y, B4[13].w, a.w);
    a.x = fmaf(t3.z, B4[14].x, a.x); a.y = fmaf(t3.z, B4[14].y, a.y);
    a.z = fmaf(t3.z, B4[14].z, a.z); a.w = fmaf(t3.z, B4[14].w, a.w);
    a.x = fmaf(t3.w, B4[15].x, a.x); a.y = fmaf(t3.w, B4[15].y, a.y);
    a.z = fmaf(t3.w, B4[15].z, a.z); a.w = fmaf(t3.w, B4[15].w, a.w);
    *reinterpret_cast<float4*>(op + (size_t)rr * 2048) = a;
  }
}

// ---------------------------------------------------------------------------
extern "C" void kernel_launch(void* const* d_in, const int* in_sizes, int n_in,
                              void* d_out, int out_size, void* d_ws, size_t ws_size,
                              hipStream_t stream) {
  const float* input = (const float*)d_in[0];   // [8][2048][2048]
  const float* w     = (const float*)d_in[1];   // [8][4][8]
  const float* la    = (const float*)d_in[2];   // [4][8][512][16]
  const float* lb    = (const float*)d_in[3];   // [4][8][16][512]
  float* outp = (float*)d_out;

  __hip_bfloat16* Amt = (__hip_bfloat16*)d_ws;                     // 512 KB
  float* Bm    = (float*)((char*)d_ws + (size_t)8 * 16 * 2048 * 2); // 1 MB
  float* tmp_p = Bm + 8 * RANK * 2048;                              // 2 MB

  skilled_lora_mix<<<512, 256, 0, stream>>>(w, la, lb, Amt, Bm);
  lora_phase_a<<<2048, 256, 0, stream>>>(input, Amt, tmp_p);
  lora_phase_b<<<2048, 256, 0, stream>>>(tmp_p, Bm, outp);
}

// Round 12
// 79.598 us; speedup vs baseline: 2.8125x; 1.0331x over previous
//
#include <hip/hip_runtime.h>
#include <hip/hip_bf16.h>
#include <cstdint>
#include <cstddef>

#define RANK 16

typedef __attribute__((ext_vector_type(8))) short bf16x8;   // 8 bf16 (4 VGPRs)
typedef __attribute__((ext_vector_type(4))) float f32x4;    // MFMA C/D

static __device__ __forceinline__ short f2bf(float f) {
  __hip_bfloat16 h = __float2bfloat16(f);
  return *reinterpret_cast<short*>(&h);
}

// ---------------------------------------------------------------------------
// Kernel 1: mix LoRA factors with per-(batch,split) skill weights.
//   Amt[b][r][k] = bf16( sum_s w[b][q][s] * la[q][s][d][r] ), k = q*512 + d
//   Bm[b][r][o]  = 2 * sum_s w[b][q][s] * lb[q][s][r][dd],   o = q*512 + dd
// (scaling folded into Bm; Bm stays fp32)                     [unchanged]
// ---------------------------------------------------------------------------
__global__ __launch_bounds__(256) void skilled_lora_mix(
    const float* __restrict__ w,       // [8][4][8]
    const float* __restrict__ la,      // [4][8][512][16]
    const float* __restrict__ lb,      // [4][8][16][512]
    __hip_bfloat16* __restrict__ Amt,  // [8][16][2048] bf16
    float* __restrict__ Bm)            // [8][16][2048] fp32, pre-scaled by 2
{
  const int j = blockIdx.x * 256 + threadIdx.x;
  if (j < 65536) {
    const int r0 = (j & 3) * 4;
    const int k  = (j >> 2) & 2047;
    const int b  = j >> 13;
    const int q  = k >> 9;
    const int d  = k & 511;
    const float* wb = w + (b * 4 + q) * 8;
    float4 acc = make_float4(0.f, 0.f, 0.f, 0.f);
#pragma unroll
    for (int s = 0; s < 8; ++s) {
      const float ws = wb[s];
      const float4 v = *reinterpret_cast<const float4*>(
          la + (size_t)(((q * 8 + s) * 512 + d) * 16 + r0));
      acc.x = fmaf(ws, v.x, acc.x);
      acc.y = fmaf(ws, v.y, acc.y);
      acc.z = fmaf(ws, v.z, acc.z);
      acc.w = fmaf(ws, v.w, acc.w);
    }
    Amt[((size_t)(b * 16 + r0 + 0)) * 2048 + k] = __float2bfloat16(acc.x);
    Amt[((size_t)(b * 16 + r0 + 1)) * 2048 + k] = __float2bfloat16(acc.y);
    Amt[((size_t)(b * 16 + r0 + 2)) * 2048 + k] = __float2bfloat16(acc.z);
    Amt[((size_t)(b * 16 + r0 + 3)) * 2048 + k] = __float2bfloat16(acc.w);
  } else {
    const int jj = j - 65536;
    const int o  = (jj & 511) * 4;
    const int r  = (jj >> 9) & 15;
    const int b  = jj >> 13;
    const int q  = o >> 9;
    const int dd = o & 511;
    const float* wb = w + (b * 4 + q) * 8;
    float4 acc = make_float4(0.f, 0.f, 0.f, 0.f);
#pragma unroll
    for (int s = 0; s < 8; ++s) {
      const float ws = wb[s];
      const float4 v = *reinterpret_cast<const float4*>(
          lb + (size_t)(((q * 8 + s) * 16 + r) * 512 + dd));
      acc.x = fmaf(ws, v.x, acc.x);
      acc.y = fmaf(ws, v.y, acc.y);
      acc.z = fmaf(ws, v.z, acc.z);
      acc.w = fmaf(ws, v.w, acc.w);
    }
    acc.x *= 2.f; acc.y *= 2.f; acc.z *= 2.f; acc.w *= 2.f;
    *reinterpret_cast<float4*>(Bm + (size_t)((b * 16 + r) * 2048 + o)) = acc;
  }
}

// ---------------------------------------------------------------------------
// Kernel 2 (phase A, MFMA + coalesced LDS re-stage):
//   tmp_p[ks][b][row][r] partial over a 1024-k half.
//
// ROUND-12: r11 proved phase A is NOT latency-bound (16 -> 32 waves/CU: no
// change). New theory: the direct fragment loads scatter each VMEM instr
// over 16 rows x 2 half-used 64B lines = 32 segments -> TA/L1 request-rate
// wall, independent of wave count. Fix: stage each 16x64-float chunk through
// wave-private LDS with FULLY COALESCED loads (lane = row*4chunk: 16 rows x
// 64B fully-used segments), then feed fragments via 2x ds_read_b128 + cvt.
//   - LDS [16][68] (pad 4): read bank-class (m+2g)&7, write (m+c)&7 -> no
//     hot conflicts beyond the inherent 1KB/instr minimum.
//   - wave-private buffer -> NO barriers in the K-loop.
//   - part[] reuses the staging LDS after a barrier: 17.4KB total.
// Grid/decomposition/MFMA math identical to r11 (validated): grid 2048 =
// 8b x 128 tiles x 2 k-splits, 256 thr; (256,8) -> 8 blocks/CU.
// C/D: col=lane&15 (=r), row=(lane>>4)*4+reg.
// ---------------------------------------------------------------------------
__global__ __launch_bounds__(256, 8) void lora_phase_a(
    const float* __restrict__ X,           // [8][2048][2048]
    const __hip_bfloat16* __restrict__ Amt,// [8][16][2048] bf16
    float* __restrict__ tmp_p)             // [2][8][2048][16] partials
{
  __shared__ float lds[4 * 16 * 68];       // 17.4 KB

  const int tid  = threadIdx.x;
  const int lane = tid & 63;
  const int wv   = tid >> 6;               // 0..3: 256-k sub-window
  const int b    = blockIdx.x >> 8;        // 8 batches
  const int tile = (blockIdx.x >> 1) & 127;
  const int ks   = blockIdx.x & 1;         // k-split 0..1
  const int row0 = tile * 16;
  const int k0   = ks * 1024 + wv * 256;
  const int m    = lane & 15;              // fragment row / r
  const int g    = lane >> 4;              // k-subgroup 0..3

  float* stage = lds + wv * (16 * 68);     // wave-private [16][68]

  const int ms = lane >> 2;                // staging row 0..15
  const int cs = (lane & 3) * 4;           // staging 16B chunk (floats)

  const float* Xb = X + ((size_t)(b * 2048 + row0)) * 2048 + k0;
  const __hip_bfloat16* Ap = Amt + ((size_t)(b * 16 + m)) * 2048 + k0 + g * 8;

  f32x4 acc = {0.f, 0.f, 0.f, 0.f};

  for (int c = 0; c < 4; ++c) {            // 4 chunks of 64 k
    const int kc = c * 64;
    // ---- stage 16 rows x 64 floats: 4 instrs, 16 rows x 64B full segments
#pragma unroll
    for (int i = 0; i < 4; ++i) {
      const float4 v = *reinterpret_cast<const float4*>(
          Xb + (size_t)ms * 2048 + kc + i * 16 + cs);
      *reinterpret_cast<float4*>(&stage[ms * 68 + i * 16 + cs]) = v;
    }
    // wave-private LDS; compiler inserts the vmcnt/lgkmcnt; no barrier.

    // ---- 2 MFMA steps (K=32 each) fed from LDS ----
#pragma unroll
    for (int h = 0; h < 2; ++h) {
      const float4 xlo = *reinterpret_cast<const float4*>(
          &stage[m * 68 + h * 32 + g * 8]);
      const float4 xhi = *reinterpret_cast<const float4*>(
          &stage[m * 68 + h * 32 + g * 8 + 4]);
      bf16x8 afrag;
      afrag[0] = f2bf(xlo.x); afrag[1] = f2bf(xlo.y);
      afrag[2] = f2bf(xlo.z); afrag[3] = f2bf(xlo.w);
      afrag[4] = f2bf(xhi.x); afrag[5] = f2bf(xhi.y);
      afrag[6] = f2bf(xhi.z); afrag[7] = f2bf(xhi.w);
      const bf16x8 bfrag = *reinterpret_cast<const bf16x8*>(
          Ap + (size_t)(c * 2 + h) * 32);
      acc = __builtin_amdgcn_mfma_f32_16x16x32_bf16(afrag, bfrag, acc, 0, 0, 0);
    }
  }

  // ---- epilogue: reuse lds as part[4][16][17] (after barrier) ----
  __syncthreads();                         // all waves done with stage
  float* part = lds;
#pragma unroll
  for (int v = 0; v < 4; ++v)
    part[(wv * 16 + g * 4 + v) * 17 + m] = acc[v];
  __syncthreads();

  const int row = tid >> 4;                // 0..15
  const int r   = tid & 15;
  const float s = part[(0 * 16 + row) * 17 + r] + part[(1 * 16 + row) * 17 + r]
                + part[(2 * 16 + row) * 17 + r] + part[(3 * 16 + row) * 17 + r];
  tmp_p[((size_t)((ks * 8 + b) * 2048 + row0 + row)) * RANK + r] = s;
}

// ---------------------------------------------------------------------------
// Kernel 3 (phase B): out[b][row][o] = sum_r (tmp0+tmp1)[b][row][r] * Bm[r][o]
// (unchanged from r11 for attribution: ~28us, near write floor)
// ---------------------------------------------------------------------------
__global__ __launch_bounds__(256, 2) void lora_phase_b(
    const float* __restrict__ tmp_p, // [2][8][2048][16] partials
    const float* __restrict__ Bm,    // [8][16][2048] (pre-scaled by 2)
    float* __restrict__ out)         // [8][2048][2048]
{
  const int tid  = threadIdx.x;
  const int b    = blockIdx.x >> 8;          // 8 batches x 256 blocks
  const int oh   = (blockIdx.x >> 7) & 1;    // column half
  const int rt   = blockIdx.x & 127;         // row tile
  const int row0 = rt * 16;
  const int o0   = oh * 1024 + tid * 4;

  const float* Bb = Bm + (size_t)b * (RANK * 2048) + o0;
  float4 B4[RANK];
#pragma unroll
  for (int r = 0; r < RANK; ++r)
    B4[r] = *reinterpret_cast<const float4*>(Bb + (size_t)r * 2048);

  const float* tp0 = tmp_p + ((size_t)(b * 2048 + row0)) * RANK;
  const float* tp1 = tmp_p + ((size_t)((8 + b) * 2048 + row0)) * RANK;
  float* op = out + ((size_t)(b * 2048 + row0)) * 2048 + o0;

#pragma unroll 4
  for (int rr = 0; rr < 16; ++rr) {
    const float4 u0 = *reinterpret_cast<const float4*>(tp0 + rr * RANK);
    const float4 u1 = *reinterpret_cast<const float4*>(tp0 + rr * RANK + 4);
    const float4 u2 = *reinterpret_cast<const float4*>(tp0 + rr * RANK + 8);
    const float4 u3 = *reinterpret_cast<const float4*>(tp0 + rr * RANK + 12);
    const float4 v0 = *reinterpret_cast<const float4*>(tp1 + rr * RANK);
    const float4 v1 = *reinterpret_cast<const float4*>(tp1 + rr * RANK + 4);
    const float4 v2 = *reinterpret_cast<const float4*>(tp1 + rr * RANK + 8);
    const float4 v3 = *reinterpret_cast<const float4*>(tp1 + rr * RANK + 12);
    const float4 t0 = make_float4(u0.x + v0.x, u0.y + v0.y, u0.z + v0.z, u0.w + v0.w);
    const float4 t1 = make_float4(u1.x + v1.x, u1.y + v1.y, u1.z + v1.z, u1.w + v1.w);
    const float4 t2 = make_float4(u2.x + v2.x, u2.y + v2.y, u2.z + v2.z, u2.w + v2.w);
    const float4 t3 = make_float4(u3.x + v3.x, u3.y + v3.y, u3.z + v3.z, u3.w + v3.w);
    float4 a = make_float4(0.f, 0.f, 0.f, 0.f);
    a.x = fmaf(t0.x, B4[0].x, a.x);  a.y = fmaf(t0.x, B4[0].y, a.y);
    a.z = fmaf(t0.x, B4[0].z, a.z);  a.w = fmaf(t0.x, B4[0].w, a.w);
    a.x = fmaf(t0.y, B4[1].x, a.x);  a.y = fmaf(t0.y, B4[1].y, a.y);
    a.z = fmaf(t0.y, B4[1].z, a.z);  a.w = fmaf(t0.y, B4[1].w, a.w);
    a.x = fmaf(t0.z, B4[2].x, a.x);  a.y = fmaf(t0.z, B4[2].y, a.y);
    a.z = fmaf(t0.z, B4[2].z, a.z);  a.w = fmaf(t0.z, B4[2].w, a.w);
    a.x = fmaf(t0.w, B4[3].x, a.x);  a.y = fmaf(t0.w, B4[3].y, a.y);
    a.z = fmaf(t0.w, B4[3].z, a.z);  a.w = fmaf(t0.w, B4[3].w, a.w);
    a.x = fmaf(t1.x, B4[4].x, a.x);  a.y = fmaf(t1.x, B4[4].y, a.y);
    a.z = fmaf(t1.x, B4[4].z, a.z);  a.w = fmaf(t1.x, B4[4].w, a.w);
    a.x = fmaf(t1.y, B4[5].x, a.x);  a.y = fmaf(t1.y, B4[5].y, a.y);
    a.z = fmaf(t1.y, B4[5].z, a.z);  a.w = fmaf(t1.y, B4[5].w, a.w);
    a.x = fmaf(t1.z, B4[6].x, a.x);  a.y = fmaf(t1.z, B4[6].y, a.y);
    a.z = fmaf(t1.z, B4[6].z, a.z);  a.w = fmaf(t1.z, B4[6].w, a.w);
    a.x = fmaf(t1.w, B4[7].x, a.x);  a.y = fmaf(t1.w, B4[7].y, a.y);
    a.z = fmaf(t1.w, B4[7].z, a.z);  a.w = fmaf(t1.w, B4[7].w, a.w);
    a.x = fmaf(t2.x, B4[8].x, a.x);  a.y = fmaf(t2.x, B4[8].y, a.y);
    a.z = fmaf(t2.x, B4[8].z, a.z);  a.w = fmaf(t2.x, B4[8].w, a.w);
    a.x = fmaf(t2.y, B4[9].x, a.x);  a.y = fmaf(t2.y, B4[9].y, a.y);
    a.z = fmaf(t2.y, B4[9].z, a.z);  a.w = fmaf(t2.y, B4[9].w, a.w);
    a.x = fmaf(t2.z, B4[10].x, a.x); a.y = fmaf(t2.z, B4[10].y, a.y);
    a.z = fmaf(t2.z, B4[10].z, a.z); a.w = fmaf(t2.z, B4[10].w, a.w);
    a.x = fmaf(t2.w, B4[11].x, a.x); a.y = fmaf(t2.w, B4[11].y, a.y);
    a.z = fmaf(t2.w, B4[11].z, a.z); a.w = fmaf(t2.w, B4[11].w, a.w);
    a.x = fmaf(t3.x, B4[12].x, a.x); a.y = fmaf(t3.x, B4[12].y, a.y);
    a.z = fmaf(t3.x, B4[12].z, a.z); a.w = fmaf(t3.x, B4[12].w, a.w);
    a.x = fmaf(t3.y, B4[13].x, a.x); a.y = fmaf(t3.y, B4[13].y, a.y);
    a.z = fmaf(t3.y, B4[13].z, a.z); a.w = fmaf(t3.y, B4[13].w, a.w);
    a.x = fmaf(t3.z, B4[14].x, a.x); a.y = fmaf(t3.z, B4[14].y, a.y);
    a.z = fmaf(t3.z, B4[14].z, a.z); a.w = fmaf(t3.z, B4[14].w, a.w);
    a.x = fmaf(t3.w, B4[15].x, a.x); a.y = fmaf(t3.w, B4[15].y, a.y);
    a.z = fmaf(t3.w, B4[15].z, a.z); a.w = fmaf(t3.w, B4[15].w, a.w);
    *reinterpret_cast<float4*>(op + (size_t)rr * 2048) = a;
  }
}

// ---------------------------------------------------------------------------
extern "C" void kernel_launch(void* const* d_in, const int* in_sizes, int n_in,
                              void* d_out, int out_size, void* d_ws, size_t ws_size,
                              hipStream_t stream) {
  const float* input = (const float*)d_in[0];   // [8][2048][2048]
  const float* w     = (const float*)d_in[1];   // [8][4][8]
  const float* la    = (const float*)d_in[2];   // [4][8][512][16]
  const float* lb    = (const float*)d_in[3];   // [4][8][16][512]
  float* outp = (float*)d_out;

  __hip_bfloat16* Amt = (__hip_bfloat16*)d_ws;                      // 512 KB
  float* Bm    = (float*)((char*)d_ws + (size_t)8 * 16 * 2048 * 2); // 1 MB
  float* tmp_p = Bm + 8 * RANK * 2048;                              // 2 MB

  skilled_lora_mix<<<512, 256, 0, stream>>>(w, la, lb, Amt, Bm);
  lora_phase_a<<<2048, 256, 0, stream>>>(input, Amt, tmp_p);
  lora_phase_b<<<2048, 256, 0, stream>>>(tmp_p, Bm, outp);
}